// Round 18
// baseline (1019.737 us; speedup 1.0000x reference)
//
#include <hip/hip_runtime.h>
#include <math.h>

#define QN 900
#define TN 100
#define CN 91
#define PN 1024
#define HWD 128
#define BS 2

typedef float f32x2 __attribute__((ext_vector_type(2)));

__device__ __forceinline__ float sigmoidf_(float x) {
    return 1.0f / (1.0f + __expf(-x));
}
__device__ __forceinline__ float softplusf_(float x) {
    return fmaxf(x, 0.0f) + __logf(1.0f + __expf(-fabsf(x)));
}
__device__ __forceinline__ unsigned bfhi(float f) {   // RNE bf16 in HIGH 16 bits
    unsigned u = __float_as_uint(f);
    return (u + 0x7FFFu + ((u >> 16) & 1u)) & 0xFFFF0000u;
}

// ---------------------------------------------------------------------------
// combo: ONE launch, 202 blocks x 1024 thr (unchanged from r17).
//  blocks [0,BS): counting-sort points by mask row -> per-slot sample table
//  blocks [BS, BS+BS*TN): tm bit-pack in ORIGINAL point order + popcounts.
// ---------------------------------------------------------------------------
__global__ __launch_bounds__(1024) void combo_kernel(
    const float2* __restrict__ coords, const int* __restrict__ tmasks,
    uint4* __restrict__ table, unsigned* __restrict__ tmw,
    float* __restrict__ tmsum)
{
    __shared__ int whist[16][HWD];
    __shared__ int woff[16][HWD];
    __shared__ int rowtot[HWD];
    __shared__ int rowbase[HWD];
    __shared__ unsigned short perm[PN];

    const int bx = blockIdx.x;
    const int tid = threadIdx.x;
    const int wv = tid >> 6, lane = tid & 63;

    if (bx < BS) {
        const int b = bx;
        ((int*)whist)[tid] = 0;
        ((int*)whist)[tid + 1024] = 0;
        __syncthreads();

        float2 cd = coords[b * PN + tid];
        float yf = cd.y * (float)HWD - 0.5f;
        int y0k = (int)floorf(yf);
        const int r = min(max(y0k, 0), HWD - 1);

        int rank = 0;
        for (int j = 0; j < 64; ++j) {
            int rj = __shfl(r, j);
            rank += (j < lane) & (rj == r);
        }
        atomicAdd(&whist[wv][r], 1);
        __syncthreads();

        if (tid < HWD) {
            int acc = 0;
#pragma unroll
            for (int w = 0; w < 16; ++w) { woff[w][tid] = acc; acc += whist[w][tid]; }
            rowtot[tid] = acc;
        }
        __syncthreads();
        if (tid == 0) {
            int acc = 0;
            for (int rr = 0; rr < HWD; ++rr) { rowbase[rr] = acc; acc += rowtot[rr]; }
        }
        __syncthreads();

        const int slot = rowbase[r] + woff[wv][r] + rank;
        perm[slot] = (unsigned short)tid;
        __syncthreads();

        const int idx = (int)perm[tid];
        cd = coords[b * PN + idx];
        float x = cd.x * (float)HWD - 0.5f;
        float y = cd.y * (float)HWD - 0.5f;
        float fx = floorf(x), fy = floorf(y);
        int x0 = (int)fx;
        int py0 = (int)fy;
        int py1 = py0 + 1;
        float wx = x - fx, wy = y - fy;
        bool bx0, bx1;
        int xl;
        if (x0 < 0)             { xl = 0;       bx0 = true;  bx1 = false; wx = 1.f - wx; }
        else if (x0 >= HWD - 1) { xl = HWD - 2; bx0 = false; bx1 = true;  wx = 1.f - wx; }
        else                    { xl = x0;      bx0 = true;  bx1 = true; }
        bool by0 = (py0 >= 0) & (py0 < HWD);
        bool by1 = (py1 >= 0) & (py1 < HWD);
        int yc0 = min(max(py0, 0), HWD - 1), yc1 = min(max(py1, 0), HWD - 1);
        unsigned ar0 = (unsigned)(yc0 * HWD + xl);
        unsigned ar1 = (unsigned)(yc1 * HWD + xl);
        unsigned fl = (unsigned)bx0 | ((unsigned)bx1 << 1) |
                      ((unsigned)by0 << 2) | ((unsigned)by1 << 3);
        uint4 te;
        te.x = ar0 | (ar1 << 14) | (fl << 28);
        te.y = __float_as_uint(wx);
        te.z = __float_as_uint(wy);
        te.w = (unsigned)idx;
        table[b * PN + tid] = te;
    } else {
        const int bt = bx - BS;
        const int b = bt / TN, t = bt % TN;
        const int* m = tmasks + (size_t)(b * TN + t) * (HWD * HWD);
        int* cnt = (int*)whist;

        float2 cd = coords[b * PN + tid];
        int xi = (int)rintf(cd.x * (float)HWD - 0.5f);
        int yi = (int)rintf(cd.y * (float)HWD - 0.5f);
        unsigned vld = (xi >= 0) & (xi < HWD) & (yi >= 0) & (yi < HWD);
        int addr = min(max(yi, 0), HWD - 1) * HWD + min(max(xi, 0), HWD - 1);
        int rv = m[addr];
        unsigned long long bal = __ballot(vld && (rv != 0));
        if (lane == 0) {
            tmw[(size_t)(b * TN + t) * 32 + wv * 2 + 0] = (unsigned)(bal & 0xFFFFFFFFull);
            tmw[(size_t)(b * TN + t) * 32 + wv * 2 + 1] = (unsigned)(bal >> 32);
            cnt[wv] = __popcll(bal);
        }
        __syncthreads();
        if (tid == 0) {
            int acc = 0;
#pragma unroll
            for (int w = 0; w < 16; ++w) acc += cnt[w];
            tmsum[b * TN + t] = (float)acc;
        }
    }
}

// ---------------------------------------------------------------------------
// Main: one block (256 thr) per PAIR of masks (b, qA=2k) and (b, qB=2k+1).
// Table/addresses/tmw/t-side scalars are q-independent -> shared. B's
// gathers are issued right after combine-A, so their latency hides under
// GEMM A + epilogue A. Straight-line (no loop-carried arrays -> no scratch).
// launch_bounds stays (256,4) (any other min-waves spills - r8/r9/r10).
// ---------------------------------------------------------------------------
__global__ __launch_bounds__(256, 4) void main_kernel(
    const float* __restrict__ logits, const float4* __restrict__ pboxes,
    const int* __restrict__ labels, const float4* __restrict__ tboxes,
    const float* __restrict__ pmasks, const uint4* __restrict__ table,
    const unsigned* __restrict__ tmw, const float* __restrict__ tmsum_,
    float* __restrict__ out, float* __restrict__ blockmax,
    int* __restrict__ badflag)
{
    __shared__ unsigned pl[2][PN];         // 8 KB packed (bf16 pm | bf16 sg)
    __shared__ float part[8][32][9];       // 9.2 KB (stride-9: conflict-free)
    __shared__ float sred[2][8];
    __shared__ float mred[256];
    __shared__ int sbad[2];

    const int bq2 = blockIdx.x;
    const int b = bq2 / (QN / 2);
    const int qA = (bq2 - b * (QN / 2)) * 2;
    const int qB = qA + 1;
    const int tid = threadIdx.x;
    const int wv = tid >> 6, lane = tid & 63;
    const int pc = tid >> 5, ts = tid & 31;
    const float* maskA = pmasks + (size_t)(b * QN + qA) * (HWD * HWD);
    const float* maskB = maskA + HWD * HWD;

    if (tid == 0) { sbad[0] = 0; sbad[1] = 0; }

    // ---- table entries (coalesced, q-independent) ----
    unsigned fl[4], orig[4];
    float wxa[4], wya[4];
    int ar0[4], ar1[4];
#pragma unroll
    for (int c = 0; c < 4; ++c) {
        uint4 te = table[b * PN + c * 256 + tid];
        ar0[c] = (int)(te.x & 16383u);
        ar1[c] = (int)((te.x >> 14) & 16383u);
        fl[c] = te.x >> 28;
        wxa[c] = __uint_as_float(te.y);
        wya[c] = __uint_as_float(te.z);
        orig[c] = te.w;
    }

    // ---- issue mask-A gathers ----
    f32x2 pA0[4], pA1[4];
#pragma unroll
    for (int c = 0; c < 4; ++c) {
        pA0[c] = *(const f32x2*)(maskA + ar0[c]);
        pA1[c] = *(const f32x2*)(maskA + ar1[c]);
    }

    // ---- under the shadow: shared tmw words + epilogue scalars ----
    const unsigned* rowb = tmw + (size_t)b * TN * 32;
    unsigned w0[4], w1[4], w2[4], w3[4];
#pragma unroll
    for (int g = 0; g < 4; ++g) {
        w0[g] = rowb[(ts +  0) * 32 + pc * 4 + g];
        w1[g] = rowb[(ts + 32) * 32 + pc * 4 + g];
        w2[g] = rowb[(ts + 64) * 32 + pc * 4 + g];
        w3[g] = (ts + 96 < TN) ? rowb[(ts + 96) * 32 + pc * 4 + g] : 0u;
    }
    float lgA = 0.f, lgB = 0.f, tsum = 0.f;
    float4 tb = make_float4(0, 0, 0, 0);
    float4 pbA = make_float4(0, 0, 0, 0), pbB = make_float4(0, 0, 0, 0);
    if (tid < TN) {
        int lab = labels[b * TN + tid];
        lgA = logits[(size_t)(b * QN + qA) * CN + lab];
        lgB = logits[(size_t)(b * QN + qB) * CN + lab];
        tsum = tmsum_[b * TN + tid];
        tb = tboxes[b * TN + tid];
        pbA = pboxes[b * QN + qA];
        pbB = pboxes[b * QN + qB];
    }

    // ---- combine A -> pl[0] ----
    float lsp = 0.f, lsm = 0.f;
#pragma unroll
    for (int c = 0; c < 4; ++c) {
        const bool bx0 = fl[c] & 1u, bx1 = fl[c] & 2u, by0 = fl[c] & 4u, by1 = fl[c] & 8u;
        float v00 = (by0 && bx0) ? pA0[c].x : 0.f;
        float v01 = (by0 && bx1) ? pA0[c].y : 0.f;
        float v10 = (by1 && bx0) ? pA1[c].x : 0.f;
        float v11 = (by1 && bx1) ? pA1[c].y : 0.f;
        float wx = wxa[c], wy = wya[c];
        float pm = (v00 * (1.f - wx) + v01 * wx) * (1.f - wy) +
                   (v10 * (1.f - wx) + v11 * wx) * wy;
        float sg = sigmoidf_(pm);
        lsp += softplusf_(pm);
        lsm += sg;
        pl[0][orig[c]] = bfhi(pm) | (bfhi(sg) >> 16);
    }
    for (int off = 32; off > 0; off >>= 1) {
        lsp += __shfl_down(lsp, off);
        lsm += __shfl_down(lsm, off);
    }
    if (lane == 0) { sred[0][wv * 2 + 0] = lsp; sred[0][wv * 2 + 1] = lsm; }

    // ---- issue mask-B gathers (hide under GEMM A + epilogue A) ----
    f32x2 pB0[4], pB1[4];
#pragma unroll
    for (int c = 0; c < 4; ++c) {
        pB0[c] = *(const f32x2*)(maskB + ar0[c]);
        pB1[c] = *(const f32x2*)(maskB + ar1[c]);
    }

    __syncthreads();   // pl[0] + sred[0] visible
    float s_sp = (sred[0][0] + sred[0][2]) + (sred[0][4] + sred[0][6]);
    float s_sm = (sred[0][1] + sred[0][3]) + (sred[0][5] + sred[0][7]);

    // ================= mask A: GEMM + epilogue =================
    {
        float a0 = 0, a1 = 0, a2 = 0, a3 = 0, a4 = 0, a5 = 0, a6 = 0, a7 = 0;
#pragma unroll
        for (int g = 0; g < 4; ++g) {
            unsigned u0 = w0[g], u1 = w1[g], u2 = w2[g], u3 = w3[g];
            int p0i = pc * 128 + g * 32;
#pragma unroll
            for (int jj = 0; jj < 8; ++jj) {
                uint4 u = *(const uint4*)&pl[0][p0i + jj * 4];
#pragma unroll
                for (int k = 0; k < 4; ++k) {
                    unsigned uv = (k == 0) ? u.x : (k == 1) ? u.y : (k == 2) ? u.z : u.w;
                    float pmv = __uint_as_float(uv & 0xFFFF0000u);
                    float sgv = __uint_as_float(uv << 16);
                    float f0 = (float)((u0 >> k) & 1u);
                    float f1 = (float)((u1 >> k) & 1u);
                    float f2 = (float)((u2 >> k) & 1u);
                    float f3 = (float)((u3 >> k) & 1u);
                    a0 = fmaf(pmv, f0, a0); a1 = fmaf(sgv, f0, a1);
                    a2 = fmaf(pmv, f1, a2); a3 = fmaf(sgv, f1, a3);
                    a4 = fmaf(pmv, f2, a4); a5 = fmaf(sgv, f2, a5);
                    a6 = fmaf(pmv, f3, a6); a7 = fmaf(sgv, f3, a7);
                }
                u0 >>= 4; u1 >>= 4; u2 >>= 4; u3 >>= 4;
            }
        }
        part[pc][ts][0] = a0; part[pc][ts][1] = a1;
        part[pc][ts][2] = a2; part[pc][ts][3] = a3;
        part[pc][ts][4] = a4; part[pc][ts][5] = a5;
        part[pc][ts][6] = a6; part[pc][ts][7] = a7;
    }
    __syncthreads();   // part (A) visible

    float val = -INFINITY;
    if (tid < TN) {
        int t = tid, tss = t & 31, kk = t >> 5;
        float apm = 0.f, asg = 0.f;
#pragma unroll
        for (int pp = 0; pp < 8; ++pp) {
            apm += part[pp][tss][kk * 2 + 0];
            asg += part[pp][tss][kk * 2 + 1];
        }
        float ce = (s_sp - apm) * (1.0f / (float)PN);
        float dice = 1.0f - (2.0f * asg + 1.0f) / (s_sm + tsum + 1.0f);

        float pr = sigmoidf_(lgA);
        float cls = 0.25f * (1.f - pr) * (1.f - pr) * softplusf_(-lgA)
                  - 0.75f * pr * pr * softplusf_(lgA);

        float l1 = fabsf(pbA.x - tb.x) + fabsf(pbA.y - tb.y) +
                   fabsf(pbA.z - tb.z) + fabsf(pbA.w - tb.w);

        float px1 = pbA.x - 0.5f * pbA.z, py1 = pbA.y - 0.5f * pbA.w;
        float px2 = pbA.x + 0.5f * pbA.z, py2 = pbA.y + 0.5f * pbA.w;
        float tx1 = tb.x - 0.5f * tb.z, ty1 = tb.y - 0.5f * tb.w;
        float tx2 = tb.x + 0.5f * tb.z, ty2 = tb.y + 0.5f * tb.w;
        float A1 = (px2 - px1) * (py2 - py1);
        float A2 = (tx2 - tx1) * (ty2 - ty1);
        float iw = fmaxf(fminf(px2, tx2) - fmaxf(px1, tx1), 0.f);
        float ih = fmaxf(fminf(py2, ty2) - fmaxf(py1, ty1), 0.f);
        float inter = iw * ih;
        float uni = A1 + A2 - inter;
        float iou = inter / uni;
        float cw = fmaxf(fmaxf(px2, tx2) - fminf(px1, tx1), 0.f);
        float chh = fmaxf(fmaxf(py2, ty2) - fminf(py1, ty1), 0.f);
        float area = cw * chh;
        float giou = iou - (area - uni) / area;

        float Cv = l1 + cls - giou + ce + dice;
        out[(size_t)(b * QN + qA) * TN + t] = Cv;
        if (isfinite(Cv)) val = Cv;
        else sbad[0] = 1;
    }
    mred[tid] = val;
    __syncthreads();   // mred (A)
    if (tid < 64) {
        float m = fmaxf(fmaxf(mred[tid], mred[tid + 64]),
                        fmaxf(mred[tid + 128], mred[tid + 192]));
        for (int off = 32; off > 0; off >>= 1)
            m = fmaxf(m, __shfl_down(m, off));
        if (tid == 0) { blockmax[b * QN + qA] = m; badflag[b * QN + qA] = sbad[0]; }
    }

    // ---- combine B -> pl[1] (taps landed under GEMM A) ----
    lsp = 0.f; lsm = 0.f;
#pragma unroll
    for (int c = 0; c < 4; ++c) {
        const bool bx0 = fl[c] & 1u, bx1 = fl[c] & 2u, by0 = fl[c] & 4u, by1 = fl[c] & 8u;
        float v00 = (by0 && bx0) ? pB0[c].x : 0.f;
        float v01 = (by0 && bx1) ? pB0[c].y : 0.f;
        float v10 = (by1 && bx0) ? pB1[c].x : 0.f;
        float v11 = (by1 && bx1) ? pB1[c].y : 0.f;
        float wx = wxa[c], wy = wya[c];
        float pm = (v00 * (1.f - wx) + v01 * wx) * (1.f - wy) +
                   (v10 * (1.f - wx) + v11 * wx) * wy;
        float sg = sigmoidf_(pm);
        lsp += softplusf_(pm);
        lsm += sg;
        pl[1][orig[c]] = bfhi(pm) | (bfhi(sg) >> 16);
    }
    for (int off = 32; off > 0; off >>= 1) {
        lsp += __shfl_down(lsp, off);
        lsm += __shfl_down(lsm, off);
    }
    if (lane == 0) { sred[1][wv * 2 + 0] = lsp; sred[1][wv * 2 + 1] = lsm; }
    __syncthreads();   // pl[1] + sred[1] visible; part(A) reads all done
    s_sp = (sred[1][0] + sred[1][2]) + (sred[1][4] + sred[1][6]);
    s_sm = (sred[1][1] + sred[1][3]) + (sred[1][5] + sred[1][7]);

    // ================= mask B: GEMM + epilogue =================
    {
        float a0 = 0, a1 = 0, a2 = 0, a3 = 0, a4 = 0, a5 = 0, a6 = 0, a7 = 0;
#pragma unroll
        for (int g = 0; g < 4; ++g) {
            unsigned u0 = w0[g], u1 = w1[g], u2 = w2[g], u3 = w3[g];
            int p0i = pc * 128 + g * 32;
#pragma unroll
            for (int jj = 0; jj < 8; ++jj) {
                uint4 u = *(const uint4*)&pl[1][p0i + jj * 4];
#pragma unroll
                for (int k = 0; k < 4; ++k) {
                    unsigned uv = (k == 0) ? u.x : (k == 1) ? u.y : (k == 2) ? u.z : u.w;
                    float pmv = __uint_as_float(uv & 0xFFFF0000u);
                    float sgv = __uint_as_float(uv << 16);
                    float f0 = (float)((u0 >> k) & 1u);
                    float f1 = (float)((u1 >> k) & 1u);
                    float f2 = (float)((u2 >> k) & 1u);
                    float f3 = (float)((u3 >> k) & 1u);
                    a0 = fmaf(pmv, f0, a0); a1 = fmaf(sgv, f0, a1);
                    a2 = fmaf(pmv, f1, a2); a3 = fmaf(sgv, f1, a3);
                    a4 = fmaf(pmv, f2, a4); a5 = fmaf(sgv, f2, a5);
                    a6 = fmaf(pmv, f3, a6); a7 = fmaf(sgv, f3, a7);
                }
                u0 >>= 4; u1 >>= 4; u2 >>= 4; u3 >>= 4;
            }
        }
        part[pc][ts][0] = a0; part[pc][ts][1] = a1;
        part[pc][ts][2] = a2; part[pc][ts][3] = a3;
        part[pc][ts][4] = a4; part[pc][ts][5] = a5;
        part[pc][ts][6] = a6; part[pc][ts][7] = a7;
    }
    __syncthreads();   // part (B) visible

    val = -INFINITY;
    if (tid < TN) {
        int t = tid, tss = t & 31, kk = t >> 5;
        float apm = 0.f, asg = 0.f;
#pragma unroll
        for (int pp = 0; pp < 8; ++pp) {
            apm += part[pp][tss][kk * 2 + 0];
            asg += part[pp][tss][kk * 2 + 1];
        }
        float ce = (s_sp - apm) * (1.0f / (float)PN);
        float dice = 1.0f - (2.0f * asg + 1.0f) / (s_sm + tsum + 1.0f);

        float pr = sigmoidf_(lgB);
        float cls = 0.25f * (1.f - pr) * (1.f - pr) * softplusf_(-lgB)
                  - 0.75f * pr * pr * softplusf_(lgB);

        float l1 = fabsf(pbB.x - tb.x) + fabsf(pbB.y - tb.y) +
                   fabsf(pbB.z - tb.z) + fabsf(pbB.w - tb.w);

        float px1 = pbB.x - 0.5f * pbB.z, py1 = pbB.y - 0.5f * pbB.w;
        float px2 = pbB.x + 0.5f * pbB.z, py2 = pbB.y + 0.5f * pbB.w;
        float tx1 = tb.x - 0.5f * tb.z, ty1 = tb.y - 0.5f * tb.w;
        float tx2 = tb.x + 0.5f * tb.z, ty2 = tb.y + 0.5f * tb.w;
        float A1 = (px2 - px1) * (py2 - py1);
        float A2 = (tx2 - tx1) * (ty2 - ty1);
        float iw = fmaxf(fminf(px2, tx2) - fmaxf(px1, tx1), 0.f);
        float ih = fmaxf(fminf(py2, ty2) - fmaxf(py1, ty1), 0.f);
        float inter = iw * ih;
        float uni = A1 + A2 - inter;
        float iou = inter / uni;
        float cw = fmaxf(fmaxf(px2, tx2) - fminf(px1, tx1), 0.f);
        float chh = fmaxf(fmaxf(py2, ty2) - fminf(py1, ty1), 0.f);
        float area = cw * chh;
        float giou = iou - (area - uni) / area;

        float Cv = l1 + cls - giou + ce + dice;
        out[(size_t)(b * QN + qB) * TN + t] = Cv;
        if (isfinite(Cv)) val = Cv;
        else sbad[1] = 1;
    }
    mred[tid] = val;
    __syncthreads();   // mred (B)
    if (tid < 64) {
        float m = fmaxf(fmaxf(mred[tid], mred[tid + 64]),
                        fmaxf(mred[tid + 128], mred[tid + 192]));
        for (int off = 32; off > 0; off >>= 1)
            m = fmaxf(m, __shfl_down(m, off));
        if (tid == 0) { blockmax[b * QN + qB] = m; badflag[b * QN + qB] = sbad[1]; }
    }
}

// ---------------------------------------------------------------------------
// Fixup: C = where(finite, C, 2*max_finite) per batch. Gated by per-row flag.
// ---------------------------------------------------------------------------
__global__ __launch_bounds__(128) void fix_kernel(float* __restrict__ out,
                                                  const float* __restrict__ blockmax,
                                                  const int* __restrict__ badflag)
{
    const int bq = blockIdx.x;
    if (badflag[bq] == 0) return;       // uniform early exit
    const int tid = threadIdx.x;
    if (tid >= TN) return;
    const int b = bq / QN;
    float v = out[(size_t)bq * TN + tid];
    if (!isfinite(v)) {
        float m = -INFINITY;
        for (int k = 0; k < QN; ++k) m = fmaxf(m, blockmax[b * QN + k]);
        out[(size_t)bq * TN + tid] = 2.0f * m;
    }
}

extern "C" void kernel_launch(void* const* d_in, const int* in_sizes, int n_in,
                              void* d_out, int out_size, void* d_ws, size_t ws_size,
                              hipStream_t stream) {
    const float* logits  = (const float*)d_in[0];
    const float4* pboxes = (const float4*)d_in[1];
    const int* labels    = (const int*)d_in[2];
    const float4* tboxes = (const float4*)d_in[3];
    const float* pmasks  = (const float*)d_in[4];
    const int* tmasks    = (const int*)d_in[5];
    const float* coords  = (const float*)d_in[6];
    float* out = (float*)d_out;

    char* ws = (char*)d_ws;
    unsigned* tmw   = (unsigned*)(ws);            // 25600 B
    float* tmsum    = (float*)(ws + 25600);       // 800 B
    float* blockmax = (float*)(ws + 26400);       // 7200 B
    int* badflag    = (int*)(ws + 33600);         // 7200 B
    uint4* table    = (uint4*)(ws + 40960);       // 32768 B

    hipLaunchKernelGGL(combo_kernel, dim3(BS + BS * TN), dim3(1024), 0, stream,
                       (const float2*)coords, tmasks, table, tmw, tmsum);
    hipLaunchKernelGGL(main_kernel, dim3(BS * QN / 2), dim3(256), 0, stream,
                       logits, pboxes, labels, tboxes, pmasks, table,
                       tmw, tmsum, out, blockmax, badflag);
    hipLaunchKernelGGL(fix_kernel, dim3(BS * QN), dim3(128), 0, stream,
                       out, blockmax, badflag);
}

// Round 19
// 50.045 us; speedup vs baseline: 20.3763x; 20.3763x over previous
//
#include <hip/hip_runtime.h>
#include <math.h>

#define QN 900
#define TN 100
#define CN 91
#define PN 1024
#define HWD 128
#define BS 2

typedef float f32x2 __attribute__((ext_vector_type(2)));

__device__ __forceinline__ float sigmoidf_(float x) {
    return 1.0f / (1.0f + __expf(-x));
}
__device__ __forceinline__ float softplusf_(float x) {
    return fmaxf(x, 0.0f) + __logf(1.0f + __expf(-fabsf(x)));
}
__device__ __forceinline__ unsigned bfhi(float f) {   // RNE bf16 in HIGH 16 bits
    unsigned u = __float_as_uint(f);
    return (u + 0x7FFFu + ((u >> 16) & 1u)) & 0xFFFF0000u;
}

// ---------------------------------------------------------------------------
// combo: ONE launch, 202 blocks x 1024 thr.
//  blocks [0,BS): counting-sort points by mask row -> per-slot sample table
//     .x = ar0 | ar1<<14 | fl<<28, .y = wx (edge-folded), .z = wy, .w = orig
//  blocks [BS, BS+BS*TN): tm bit-pack in ORIGINAL point order + popcounts
//     (independent of the sort -> runs concurrently on the other CUs).
// Gather order (sorted) is decoupled from data order (original): main
// scatter-writes pl[orig], so tmw/GEMM stay in original order.
// ---------------------------------------------------------------------------
__global__ __launch_bounds__(1024) void combo_kernel(
    const float2* __restrict__ coords, const int* __restrict__ tmasks,
    uint4* __restrict__ table, unsigned* __restrict__ tmw,
    float* __restrict__ tmsum)
{
    __shared__ int whist[16][HWD];      // 8 KB (sort) / reused as cnt (prep)
    __shared__ int woff[16][HWD];       // 8 KB
    __shared__ int rowtot[HWD];
    __shared__ int rowbase[HWD];
    __shared__ unsigned short perm[PN];

    const int bx = blockIdx.x;
    const int tid = threadIdx.x;
    const int wv = tid >> 6, lane = tid & 63;

    if (bx < BS) {
        // ---------------- sort path ----------------
        const int b = bx;
        ((int*)whist)[tid] = 0;
        ((int*)whist)[tid + 1024] = 0;
        __syncthreads();

        float2 cd = coords[b * PN + tid];
        float yf = cd.y * (float)HWD - 0.5f;
        int y0k = (int)floorf(yf);
        const int r = min(max(y0k, 0), HWD - 1);

        int rank = 0;
        for (int j = 0; j < 64; ++j) {
            int rj = __shfl(r, j);
            rank += (j < lane) & (rj == r);
        }
        atomicAdd(&whist[wv][r], 1);
        __syncthreads();

        if (tid < HWD) {
            int acc = 0;
#pragma unroll
            for (int w = 0; w < 16; ++w) { woff[w][tid] = acc; acc += whist[w][tid]; }
            rowtot[tid] = acc;
        }
        __syncthreads();
        if (tid == 0) {
            int acc = 0;
            for (int rr = 0; rr < HWD; ++rr) { rowbase[rr] = acc; acc += rowtot[rr]; }
        }
        __syncthreads();

        const int slot = rowbase[r] + woff[wv][r] + rank;
        perm[slot] = (unsigned short)tid;
        __syncthreads();

        const int idx = (int)perm[tid];
        cd = coords[b * PN + idx];
        float x = cd.x * (float)HWD - 0.5f;
        float y = cd.y * (float)HWD - 0.5f;
        float fx = floorf(x), fy = floorf(y);
        int x0 = (int)fx;
        int py0 = (int)fy;
        int py1 = py0 + 1;
        float wx = x - fx, wy = y - fy;
        bool bx0, bx1;
        int xl;
        if (x0 < 0)             { xl = 0;       bx0 = true;  bx1 = false; wx = 1.f - wx; }
        else if (x0 >= HWD - 1) { xl = HWD - 2; bx0 = false; bx1 = true;  wx = 1.f - wx; }
        else                    { xl = x0;      bx0 = true;  bx1 = true; }
        bool by0 = (py0 >= 0) & (py0 < HWD);
        bool by1 = (py1 >= 0) & (py1 < HWD);
        int yc0 = min(max(py0, 0), HWD - 1), yc1 = min(max(py1, 0), HWD - 1);
        unsigned ar0 = (unsigned)(yc0 * HWD + xl);
        unsigned ar1 = (unsigned)(yc1 * HWD + xl);
        unsigned fl = (unsigned)bx0 | ((unsigned)bx1 << 1) |
                      ((unsigned)by0 << 2) | ((unsigned)by1 << 3);
        uint4 te;
        te.x = ar0 | (ar1 << 14) | (fl << 28);
        te.y = __float_as_uint(wx);
        te.z = __float_as_uint(wy);
        te.w = (unsigned)idx;
        table[b * PN + tid] = te;
    } else {
        // ---------------- prep path (original point order) ----------------
        const int bt = bx - BS;               // [0, 200)
        const int b = bt / TN, t = bt % TN;
        const int* m = tmasks + (size_t)(b * TN + t) * (HWD * HWD);
        int* cnt = (int*)whist;               // reuse LDS

        float2 cd = coords[b * PN + tid];
        int xi = (int)rintf(cd.x * (float)HWD - 0.5f);
        int yi = (int)rintf(cd.y * (float)HWD - 0.5f);
        unsigned vld = (xi >= 0) & (xi < HWD) & (yi >= 0) & (yi < HWD);
        int addr = min(max(yi, 0), HWD - 1) * HWD + min(max(xi, 0), HWD - 1);
        int rv = m[addr];
        unsigned long long bal = __ballot(vld && (rv != 0));
        if (lane == 0) {
            tmw[(size_t)(b * TN + t) * 32 + wv * 2 + 0] = (unsigned)(bal & 0xFFFFFFFFull);
            tmw[(size_t)(b * TN + t) * 32 + wv * 2 + 1] = (unsigned)(bal >> 32);
            cnt[wv] = __popcll(bal);
        }
        __syncthreads();
        if (tid == 0) {
            int acc = 0;
#pragma unroll
            for (int w = 0; w < 16; ++w) acc += cnt[w];
            tmsum[b * TN + t] = (float)acc;
        }
    }
}

// ---------------------------------------------------------------------------
// Main: one block (256 thr) per (b,q). Sorted gathers via table; pl scatter-
// written at ORIGINAL index so the bit-GEMM matches original-order tmw.
// launch_bounds stays (256,4) (any other min-waves spills - r8/r9/r10;
// cross-GEMM live state also spills - r18).
// ---------------------------------------------------------------------------
__global__ __launch_bounds__(256, 4) void main_kernel(
    const float* __restrict__ logits, const float4* __restrict__ pboxes,
    const int* __restrict__ labels, const float4* __restrict__ tboxes,
    const float* __restrict__ pmasks, const uint4* __restrict__ table,
    const unsigned* __restrict__ tmw, const float* __restrict__ tmsum_,
    float* __restrict__ out, float* __restrict__ blockmax,
    int* __restrict__ badflag)
{
    __shared__ unsigned pl[PN];            // 4 KB packed (bf16 pm | bf16 sg)
    __shared__ float part[8][32][9];       // 9.2 KB (stride-9: conflict-free)
    __shared__ float sred[8];
    __shared__ float mred[256];
    __shared__ int sbad;

    const int bq = blockIdx.x;
    const int b = bq / QN, q = bq - b * QN;
    const int tid = threadIdx.x;
    const int wv = tid >> 6, lane = tid & 63;
    const int pc = tid >> 5, ts = tid & 31;
    const float* mask = pmasks + (size_t)bq * (HWD * HWD);

    if (tid == 0) sbad = 0;

    // ---- table entries (coalesced): sorted pair addresses + orig index ----
    unsigned fl[4], orig[4];
    float wxa[4], wya[4];
    int ar0[4], ar1[4];
#pragma unroll
    for (int c = 0; c < 4; ++c) {
        uint4 te = table[b * PN + c * 256 + tid];
        ar0[c] = (int)(te.x & 16383u);
        ar1[c] = (int)((te.x >> 14) & 16383u);
        fl[c] = te.x >> 28;
        wxa[c] = __uint_as_float(te.y);
        wya[c] = __uint_as_float(te.z);
        orig[c] = te.w;
    }

    // ---- issue ALL 8 paired sorted gathers up front ----
    f32x2 p0[4], p1[4];
#pragma unroll
    for (int c = 0; c < 4; ++c) {
        p0[c] = *(const f32x2*)(mask + ar0[c]);
        p1[c] = *(const f32x2*)(mask + ar1[c]);
    }

    // ---- under the shadow: tmw words + epilogue scalars ----
    const unsigned* rowb = tmw + (size_t)b * TN * 32;
    unsigned w0[4], w1[4], w2[4], w3[4];
#pragma unroll
    for (int g = 0; g < 4; ++g) {
        w0[g] = rowb[(ts +  0) * 32 + pc * 4 + g];
        w1[g] = rowb[(ts + 32) * 32 + pc * 4 + g];
        w2[g] = rowb[(ts + 64) * 32 + pc * 4 + g];
        w3[g] = (ts + 96 < TN) ? rowb[(ts + 96) * 32 + pc * 4 + g] : 0u;
    }
    float lg = 0.f, tsum = 0.f;
    float4 tb = make_float4(0, 0, 0, 0), pb = make_float4(0, 0, 0, 0);
    if (tid < TN) {
        int lab = labels[b * TN + tid];
        lg = logits[(size_t)(b * QN + q) * CN + lab];
        tsum = tmsum_[b * TN + tid];
        tb = tboxes[b * TN + tid];
        pb = pboxes[b * QN + q];
    }

    // ---- bilinear combine + transcendental -> pl[orig] (LDS scatter) ----
    float lsp = 0.f, lsm = 0.f;
#pragma unroll
    for (int c = 0; c < 4; ++c) {
        const bool bx0 = fl[c] & 1u, bx1 = fl[c] & 2u, by0 = fl[c] & 4u, by1 = fl[c] & 8u;
        float v00 = (by0 && bx0) ? p0[c].x : 0.f;
        float v01 = (by0 && bx1) ? p0[c].y : 0.f;
        float v10 = (by1 && bx0) ? p1[c].x : 0.f;
        float v11 = (by1 && bx1) ? p1[c].y : 0.f;
        float wx = wxa[c], wy = wya[c];
        float pm = (v00 * (1.f - wx) + v01 * wx) * (1.f - wy) +
                   (v10 * (1.f - wx) + v11 * wx) * wy;
        float sg = sigmoidf_(pm);
        lsp += softplusf_(pm);
        lsm += sg;
        pl[orig[c]] = bfhi(pm) | (bfhi(sg) >> 16);
    }
    for (int off = 32; off > 0; off >>= 1) {
        lsp += __shfl_down(lsp, off);
        lsm += __shfl_down(lsm, off);
    }
    if (lane == 0) { sred[wv * 2 + 0] = lsp; sred[wv * 2 + 1] = lsm; }
    __syncthreads();
    float s_sp = (sred[0] + sred[2]) + (sred[4] + sred[6]);
    float s_sm = (sred[1] + sred[3]) + (sred[5] + sred[7]);

    // ---- bit-masked dual GEMM: chunk pc (128 points) x 4 targets ----
    float a0 = 0, a1 = 0, a2 = 0, a3 = 0, a4 = 0, a5 = 0, a6 = 0, a7 = 0;
#pragma unroll
    for (int g = 0; g < 4; ++g) {
        unsigned u0 = w0[g], u1 = w1[g], u2 = w2[g], u3 = w3[g];
        int p0i = pc * 128 + g * 32;
#pragma unroll
        for (int jj = 0; jj < 8; ++jj) {
            uint4 u = *(const uint4*)&pl[p0i + jj * 4];   // broadcast within half-wave
#pragma unroll
            for (int k = 0; k < 4; ++k) {
                unsigned uv = (k == 0) ? u.x : (k == 1) ? u.y : (k == 2) ? u.z : u.w;
                float pmv = __uint_as_float(uv & 0xFFFF0000u);
                float sgv = __uint_as_float(uv << 16);
                float f0 = (float)((u0 >> k) & 1u);
                float f1 = (float)((u1 >> k) & 1u);
                float f2 = (float)((u2 >> k) & 1u);
                float f3 = (float)((u3 >> k) & 1u);
                a0 = fmaf(pmv, f0, a0); a1 = fmaf(sgv, f0, a1);
                a2 = fmaf(pmv, f1, a2); a3 = fmaf(sgv, f1, a3);
                a4 = fmaf(pmv, f2, a4); a5 = fmaf(sgv, f2, a5);
                a6 = fmaf(pmv, f3, a6); a7 = fmaf(sgv, f3, a7);
            }
            u0 >>= 4; u1 >>= 4; u2 >>= 4; u3 >>= 4;
        }
    }
    part[pc][ts][0] = a0; part[pc][ts][1] = a1;
    part[pc][ts][2] = a2; part[pc][ts][3] = a3;
    part[pc][ts][4] = a4; part[pc][ts][5] = a5;
    part[pc][ts][6] = a6; part[pc][ts][7] = a7;
    __syncthreads();

    // ---- epilogue ----
    float val = -INFINITY;
    if (tid < TN) {
        int t = tid, tss = t & 31, kk = t >> 5;
        float apm = 0.f, asg = 0.f;
#pragma unroll
        for (int pp = 0; pp < 8; ++pp) {
            apm += part[pp][tss][kk * 2 + 0];
            asg += part[pp][tss][kk * 2 + 1];
        }
        float ce = (s_sp - apm) * (1.0f / (float)PN);
        float dice = 1.0f - (2.0f * asg + 1.0f) / (s_sm + tsum + 1.0f);

        float pr = sigmoidf_(lg);
        float cls = 0.25f * (1.f - pr) * (1.f - pr) * softplusf_(-lg)
                  - 0.75f * pr * pr * softplusf_(lg);

        float l1 = fabsf(pb.x - tb.x) + fabsf(pb.y - tb.y) +
                   fabsf(pb.z - tb.z) + fabsf(pb.w - tb.w);

        float px1 = pb.x - 0.5f * pb.z, py1 = pb.y - 0.5f * pb.w;
        float px2 = pb.x + 0.5f * pb.z, py2 = pb.y + 0.5f * pb.w;
        float tx1 = tb.x - 0.5f * tb.z, ty1 = tb.y - 0.5f * tb.w;
        float tx2 = tb.x + 0.5f * tb.z, ty2 = tb.y + 0.5f * tb.w;
        float A1 = (px2 - px1) * (py2 - py1);
        float A2 = (tx2 - tx1) * (ty2 - ty1);
        float iw = fmaxf(fminf(px2, tx2) - fmaxf(px1, tx1), 0.f);
        float ih = fmaxf(fminf(py2, ty2) - fmaxf(py1, ty1), 0.f);
        float inter = iw * ih;
        float uni = A1 + A2 - inter;
        float iou = inter / uni;
        float cw = fmaxf(fmaxf(px2, tx2) - fminf(px1, tx1), 0.f);
        float chh = fmaxf(fmaxf(py2, ty2) - fminf(py1, ty1), 0.f);
        float area = cw * chh;
        float giou = iou - (area - uni) / area;

        float Cv = l1 + cls - giou + ce + dice;
        out[(size_t)(b * QN + q) * TN + t] = Cv;
        if (isfinite(Cv)) val = Cv;
        else sbad = 1;             // benign same-value race
    }
    mred[tid] = val;
    __syncthreads();
    if (tid < 64) {
        float m = fmaxf(fmaxf(mred[tid], mred[tid + 64]),
                        fmaxf(mred[tid + 128], mred[tid + 192]));
        for (int off = 32; off > 0; off >>= 1)
            m = fmaxf(m, __shfl_down(m, off));
        if (tid == 0) { blockmax[bq] = m; badflag[bq] = sbad; }
    }
}

// ---------------------------------------------------------------------------
// Fixup: C = where(finite, C, 2*max_finite) per batch. Gated by per-row flag.
// ---------------------------------------------------------------------------
__global__ __launch_bounds__(128) void fix_kernel(float* __restrict__ out,
                                                  const float* __restrict__ blockmax,
                                                  const int* __restrict__ badflag)
{
    const int bq = blockIdx.x;
    if (badflag[bq] == 0) return;       // uniform early exit
    const int tid = threadIdx.x;
    if (tid >= TN) return;
    const int b = bq / QN;
    float v = out[(size_t)bq * TN + tid];
    if (!isfinite(v)) {
        float m = -INFINITY;
        for (int k = 0; k < QN; ++k) m = fmaxf(m, blockmax[b * QN + k]);
        out[(size_t)bq * TN + tid] = 2.0f * m;
    }
}

extern "C" void kernel_launch(void* const* d_in, const int* in_sizes, int n_in,
                              void* d_out, int out_size, void* d_ws, size_t ws_size,
                              hipStream_t stream) {
    const float* logits  = (const float*)d_in[0];
    const float4* pboxes = (const float4*)d_in[1];
    const int* labels    = (const int*)d_in[2];
    const float4* tboxes = (const float4*)d_in[3];
    const float* pmasks  = (const float*)d_in[4];
    const int* tmasks    = (const int*)d_in[5];
    const float* coords  = (const float*)d_in[6];
    float* out = (float*)d_out;

    char* ws = (char*)d_ws;
    unsigned* tmw   = (unsigned*)(ws);            // 25600 B
    float* tmsum    = (float*)(ws + 25600);       // 800 B
    float* blockmax = (float*)(ws + 26400);       // 7200 B
    int* badflag    = (int*)(ws + 33600);         // 7200 B
    uint4* table    = (uint4*)(ws + 40960);       // 32768 B

    hipLaunchKernelGGL(combo_kernel, dim3(BS + BS * TN), dim3(1024), 0, stream,
                       (const float2*)coords, tmasks, table, tmw, tmsum);
    hipLaunchKernelGGL(main_kernel, dim3(BS * QN), dim3(256), 0, stream,
                       logits, pboxes, labels, tboxes, pmasks, table,
                       tmw, tmsum, out, blockmax, badflag);
    hipLaunchKernelGGL(fix_kernel, dim3(BS * QN), dim3(128), 0, stream,
                       out, blockmax, badflag);
}